// Round 1
// baseline (564.340 us; speedup 1.0000x reference)
//
#include <hip/hip_runtime.h>
#include <stdint.h>

// Problem: out = ol_quant(x) with th = exact order statistic of |x| at
// idx = floor(0.997f * nnz) + n_zeros  (0-based, clamped to n-1),
// step = th/7, q = round_half_even(x/step)*step,
// out = (th>0 && |x|<=th) ? q : x.
//
// Selection via 2-level radix histogram on the 31-bit magnitude bit pattern
// (monotone in value for non-negative floats): 12 coarse bits (LDS-privatized)
// + 19 fine bits (global atomics, only elements matching the coarse bucket).
// 12 + 19 = 31 bits -> the recovered bit pattern is the EXACT threshold value.

#define COARSE_BITS 12
#define FINE_BITS   19
#define NCOARSE     (1u << COARSE_BITS)   // 4096
#define NFINE       (1u << FINE_BITS)     // 524288
#define NPART       256
#define CHUNK       (NFINE / NPART)       // 2048

// ws layout in u32 words:
//   [0] coarse bucket b   [1] rank within coarse bucket   [2] th_bits
//   [4] zero count
//   [64 .. 64+4096)          coarse histogram
//   [4224 .. 4224+524288)    fine histogram
//   [528512 .. 528512+256)   chunk partial sums
#define WS_CTRL   0
#define WS_COARSE 64
#define WS_FINE   4224
#define WS_PART   (WS_FINE + NFINE)
#define WS_WORDS  (WS_PART + NPART)

__global__ __launch_bounds__(256) void k_hist(const uint32_t* __restrict__ x,
                                              int n, uint32_t* __restrict__ ws) {
    __shared__ uint32_t h[NCOARSE];
    __shared__ uint32_t zc;
    for (int i = threadIdx.x; i < (int)NCOARSE; i += 256) h[i] = 0;
    if (threadIdx.x == 0) zc = 0;
    __syncthreads();

    const int n4 = n >> 2;
    const uint4* x4 = (const uint4*)x;
    const int stride = gridDim.x * blockDim.x;
    uint32_t myz = 0;
    for (int i = blockIdx.x * blockDim.x + threadIdx.x; i < n4; i += stride) {
        uint4 v = x4[i];
        uint32_t m0 = v.x & 0x7FFFFFFFu, m1 = v.y & 0x7FFFFFFFu;
        uint32_t m2 = v.z & 0x7FFFFFFFu, m3 = v.w & 0x7FFFFFFFu;
        atomicAdd(&h[m0 >> FINE_BITS], 1u);
        atomicAdd(&h[m1 >> FINE_BITS], 1u);
        atomicAdd(&h[m2 >> FINE_BITS], 1u);
        atomicAdd(&h[m3 >> FINE_BITS], 1u);
        myz += (m0 == 0u) + (m1 == 0u) + (m2 == 0u) + (m3 == 0u);
    }
    // scalar tail (n not multiple of 4)
    for (int i = (n4 << 2) + blockIdx.x * blockDim.x + threadIdx.x; i < n; i += stride) {
        uint32_t m = x[i] & 0x7FFFFFFFu;
        atomicAdd(&h[m >> FINE_BITS], 1u);
        myz += (m == 0u);
    }
    if (myz) atomicAdd(&zc, myz);
    __syncthreads();
    for (int i = threadIdx.x; i < (int)NCOARSE; i += 256) {
        uint32_t c = h[i];
        if (c) atomicAdd(&ws[WS_COARSE + i], c);
    }
    if (threadIdx.x == 0 && zc) atomicAdd(&ws[WS_CTRL + 4], zc);
}

__global__ __launch_bounds__(256) void k_select_coarse(uint32_t* __restrict__ ws, int n) {
    __shared__ uint32_t sums[256];
    __shared__ uint32_t ex[256];
    __shared__ uint32_t tgt;
    const int t = threadIdx.x;
    uint32_t local[16];
    uint32_t s = 0;
    for (int i = 0; i < 16; ++i) { local[i] = ws[WS_COARSE + t * 16 + i]; s += local[i]; }
    sums[t] = s;
    __syncthreads();
    if (t == 0) {
        uint32_t zeros = ws[WS_CTRL + 4];
        uint32_t nnz = (uint32_t)n - zeros;
        // replicate reference: floor(f32(0.997) * f32(nnz)) + zeros, clamp to n-1
        long long idx = (long long)floorf(0.997f * (float)nnz) + (long long)zeros;
        if (idx > (long long)n - 1) idx = (long long)n - 1;
        tgt = (uint32_t)idx;
        uint32_t run = 0;
        for (int i = 0; i < 256; ++i) { ex[i] = run; run += sums[i]; }
    }
    __syncthreads();
    const uint32_t r = tgt;
    if (r >= ex[t] && r < ex[t] + sums[t]) {
        uint32_t run = ex[t];
        for (int i = 0; i < 16; ++i) {
            if (r < run + local[i]) {
                ws[WS_CTRL + 0] = (uint32_t)(t * 16 + i);
                ws[WS_CTRL + 1] = r - run;
                break;
            }
            run += local[i];
        }
    }
}

__global__ __launch_bounds__(256) void k_fine(const uint32_t* __restrict__ x,
                                              int n, uint32_t* __restrict__ ws) {
    const uint32_t b = ws[WS_CTRL + 0];
    const int n4 = n >> 2;
    const uint4* x4 = (const uint4*)x;
    const int stride = gridDim.x * blockDim.x;
    for (int i = blockIdx.x * blockDim.x + threadIdx.x; i < n4; i += stride) {
        uint4 v = x4[i];
        uint32_t m;
        m = v.x & 0x7FFFFFFFu; if ((m >> FINE_BITS) == b) atomicAdd(&ws[WS_FINE + (m & (NFINE - 1u))], 1u);
        m = v.y & 0x7FFFFFFFu; if ((m >> FINE_BITS) == b) atomicAdd(&ws[WS_FINE + (m & (NFINE - 1u))], 1u);
        m = v.z & 0x7FFFFFFFu; if ((m >> FINE_BITS) == b) atomicAdd(&ws[WS_FINE + (m & (NFINE - 1u))], 1u);
        m = v.w & 0x7FFFFFFFu; if ((m >> FINE_BITS) == b) atomicAdd(&ws[WS_FINE + (m & (NFINE - 1u))], 1u);
    }
    for (int i = (n4 << 2) + blockIdx.x * blockDim.x + threadIdx.x; i < n; i += stride) {
        uint32_t m = x[i] & 0x7FFFFFFFu;
        if ((m >> FINE_BITS) == b) atomicAdd(&ws[WS_FINE + (m & (NFINE - 1u))], 1u);
    }
}

__global__ __launch_bounds__(256) void k_partials(uint32_t* __restrict__ ws) {
    __shared__ uint32_t red[256];
    const int t = threadIdx.x, j = blockIdx.x;
    uint32_t s = 0;
    for (int k = 0; k < CHUNK / 256; ++k) s += ws[WS_FINE + j * CHUNK + k * 256 + t];
    red[t] = s;
    __syncthreads();
    for (int o = 128; o > 0; o >>= 1) {
        if (t < o) red[t] += red[t + o];
        __syncthreads();
    }
    if (t == 0) ws[WS_PART + j] = red[0];
}

__global__ __launch_bounds__(256) void k_select_fine(uint32_t* __restrict__ ws) {
    __shared__ uint32_t sums[256];
    __shared__ uint32_t ex[256];
    __shared__ uint32_t chunk, r3;
    const int t = threadIdx.x;
    sums[t] = ws[WS_PART + t];
    __syncthreads();
    if (t == 0) {
        uint32_t r2 = ws[WS_CTRL + 1];
        uint32_t run = 0; int c = -1; uint32_t rr = 0;
        for (int i = 0; i < 256; ++i) {
            if (c < 0 && r2 < run + sums[i]) { c = i; rr = r2 - run; }
            run += sums[i];
        }
        chunk = (uint32_t)c;
        r3 = rr;
    }
    __syncthreads();
    const uint32_t c = chunk;
    uint32_t local[CHUNK / 256];
    uint32_t s = 0;
    for (int k = 0; k < CHUNK / 256; ++k) {
        local[k] = ws[WS_FINE + c * CHUNK + t * (CHUNK / 256) + k];
        s += local[k];
    }
    sums[t] = s;
    __syncthreads();
    if (t == 0) {
        uint32_t run = 0;
        for (int i = 0; i < 256; ++i) { ex[i] = run; run += sums[i]; }
    }
    __syncthreads();
    const uint32_t r = r3;
    if (r >= ex[t] && r < ex[t] + s) {
        uint32_t run = ex[t];
        for (int k = 0; k < CHUNK / 256; ++k) {
            if (r < run + local[k]) {
                uint32_t f = c * CHUNK + (uint32_t)t * (CHUNK / 256) + (uint32_t)k;
                uint32_t b = ws[WS_CTRL + 0];
                ws[WS_CTRL + 2] = (b << FINE_BITS) | f;
                break;
            }
            run += local[k];
        }
    }
}

__device__ __forceinline__ float ol_q(float v, float th, float step) {
    // q computed unconditionally; outliers (and th==0) keep v.
    float q = rintf(v / step) * step;   // rintf == v_rndne == jnp.round (half-to-even)
    return (th > 0.0f && fabsf(v) <= th) ? q : v;
}

__global__ __launch_bounds__(256) void k_quant(const float* __restrict__ x,
                                               float* __restrict__ out,
                                               const uint32_t* __restrict__ ws, int n) {
    const float th = __uint_as_float(ws[WS_CTRL + 2]);
    const float step = th / 7.0f;      // n_lv_pos = 2^(4-1)-1 = 7
    const int n4 = n >> 2;
    const float4* x4 = (const float4*)x;
    float4* o4 = (float4*)out;
    const int stride = gridDim.x * blockDim.x;
    for (int i = blockIdx.x * blockDim.x + threadIdx.x; i < n4; i += stride) {
        float4 v = x4[i];
        float4 o;
        o.x = ol_q(v.x, th, step);
        o.y = ol_q(v.y, th, step);
        o.z = ol_q(v.z, th, step);
        o.w = ol_q(v.w, th, step);
        o4[i] = o;
    }
    for (int i = (n4 << 2) + blockIdx.x * blockDim.x + threadIdx.x; i < n; i += stride) {
        out[i] = ol_q(x[i], th, step);
    }
}

extern "C" void kernel_launch(void* const* d_in, const int* in_sizes, int n_in,
                              void* d_out, int out_size, void* d_ws, size_t ws_size,
                              hipStream_t stream) {
    const float* x = (const float*)d_in[0];
    const uint32_t* xb = (const uint32_t*)d_in[0];
    float* out = (float*)d_out;
    uint32_t* ws = (uint32_t*)d_ws;
    const int n = in_sizes[0];

    // zero control block + histograms (ws is poisoned to 0xAA before every call)
    hipMemsetAsync(d_ws, 0, (size_t)WS_WORDS * sizeof(uint32_t), stream);

    const int blocks = 2048;
    k_hist<<<blocks, 256, 0, stream>>>(xb, n, ws);
    k_select_coarse<<<1, 256, 0, stream>>>(ws, n);
    k_fine<<<blocks, 256, 0, stream>>>(xb, n, ws);
    k_partials<<<NPART, 256, 0, stream>>>(ws);
    k_select_fine<<<1, 256, 0, stream>>>(ws);
    k_quant<<<blocks, 256, 0, stream>>>(x, out, ws, n);
}

// Round 2
// 537.689 us; speedup vs baseline: 1.0496x; 1.0496x over previous
//
#include <hip/hip_runtime.h>
#include <stdint.h>

// out = ol_quant(x): th = exact order statistic of |x| at
// idx = floor(0.997f * f32(nnz)) + n_zeros  (0-based, clamped n-1),
// step = th/7, q = rndne(x/step)*step, out = (th>0 && |x|<=th) ? q : x.
//
// Exact selection via 2-level radix on the 31-bit magnitude pattern
// (monotone for non-negative floats): 12 coarse bits (LDS histogram)
// + 19 fine bits. Pass 1 additionally COMPACTS candidates (|x| >= 2.0,
// i.e. coarse bucket >= 2048 — pivot aligns with a bucket boundary) into
// per-block private regions, so the fine pass reads ~12 MB instead of
// 256 MB. Device-verified: if th bucket < 2048 or any region overflowed,
// an always-launched full-scan fallback kernel does the fine histogram.

#define COARSE_BITS 12
#define FINE_BITS   19
#define NCOARSE     (1u << COARSE_BITS)   // 4096
#define NFINE       (1u << FINE_BITS)     // 524288
#define NPART       256
#define CHUNK       (NFINE / NPART)       // 2048
#define NBLOCKS     2048
#define CAP         4096                  // per-block candidate capacity (exp ~1490)
#define PIVOT_BITS  0x40000000u           // 2.0f; PIVOT_BITS>>FINE_BITS == 2048

// ws layout (u32 words):
//  ctrl: [0] coarse bucket b  [1] rank in bucket  [2] th_bits
//        [3] use_compact flag [4] zero count      [5] overflow flag
#define WS_CTRL   0
#define WS_COARSE 64
#define WS_FINE   4224
#define WS_PART   (WS_FINE + NFINE)
#define WS_BCNT   (WS_PART + NPART)
#define WS_ZERO_WORDS (WS_BCNT + NBLOCKS)        // words to memset (~2.1 MB)
#define WS_CAND   (WS_BCNT + NBLOCKS)            // regions: NBLOCKS*CAP words (~32 MB), not zeroed
// NOTE: WS_CAND aliases nothing; WS_ZERO_WORDS == WS_CAND start (regions not zeroed).

__global__ __launch_bounds__(256) void k_histc(const uint32_t* __restrict__ x,
                                               int n, uint32_t* __restrict__ ws) {
    __shared__ uint32_t h[2][NCOARSE];   // wave-parity replicas: halve hot-bucket contention
    __shared__ uint32_t zc, bcnt;
    for (int i = threadIdx.x; i < (int)NCOARSE; i += 256) { h[0][i] = 0; h[1][i] = 0; }
    if (threadIdx.x == 0) { zc = 0; bcnt = 0; }
    __syncthreads();

    const int lane = threadIdx.x & 63;
    uint32_t* hh = h[(threadIdx.x >> 6) & 1];
    uint32_t* region = ws + WS_CAND + (size_t)blockIdx.x * CAP;

    const int n4 = n >> 2;
    const uint4* x4 = (const uint4*)x;
    const int stride = gridDim.x * blockDim.x;
    uint32_t myz = 0;
    for (int i = blockIdx.x * blockDim.x + threadIdx.x; i < n4; i += stride) {
        uint4 v = x4[i];
        uint32_t m0 = v.x & 0x7FFFFFFFu, m1 = v.y & 0x7FFFFFFFu;
        uint32_t m2 = v.z & 0x7FFFFFFFu, m3 = v.w & 0x7FFFFFFFu;
        atomicAdd(&hh[m0 >> FINE_BITS], 1u);
        atomicAdd(&hh[m1 >> FINE_BITS], 1u);
        atomicAdd(&hh[m2 >> FINE_BITS], 1u);
        atomicAdd(&hh[m3 >> FINE_BITS], 1u);
        myz += (m0 == 0u) + (m1 == 0u) + (m2 == 0u) + (m3 == 0u);

        // wave-aggregated compaction of candidates (|x| >= 2.0)
        unsigned long long b0 = __ballot(m0 >= PIVOT_BITS);
        unsigned long long b1 = __ballot(m1 >= PIVOT_BITS);
        unsigned long long b2 = __ballot(m2 >= PIVOT_BITS);
        unsigned long long b3 = __ballot(m3 >= PIVOT_BITS);
        uint32_t c0 = (uint32_t)__popcll(b0);
        uint32_t c1 = (uint32_t)__popcll(b1);
        uint32_t c2 = (uint32_t)__popcll(b2);
        uint32_t c3 = (uint32_t)__popcll(b3);
        uint32_t tot = c0 + c1 + c2 + c3;
        if (tot) {
            uint32_t wbase = 0;
            if (lane == 0) wbase = atomicAdd(&bcnt, tot);
            wbase = (uint32_t)__shfl((int)wbase, 0, 64);
            unsigned long long lt = (1ULL << lane) - 1ULL;
            if (m0 >= PIVOT_BITS) { uint32_t p = wbase + (uint32_t)__popcll(b0 & lt);                 if (p < CAP) region[p] = m0; }
            if (m1 >= PIVOT_BITS) { uint32_t p = wbase + c0 + (uint32_t)__popcll(b1 & lt);            if (p < CAP) region[p] = m1; }
            if (m2 >= PIVOT_BITS) { uint32_t p = wbase + c0 + c1 + (uint32_t)__popcll(b2 & lt);       if (p < CAP) region[p] = m2; }
            if (m3 >= PIVOT_BITS) { uint32_t p = wbase + c0 + c1 + c2 + (uint32_t)__popcll(b3 & lt);  if (p < CAP) region[p] = m3; }
        }
    }
    // scalar tail (n not multiple of 4)
    for (int i = (n4 << 2) + blockIdx.x * blockDim.x + threadIdx.x; i < n; i += stride) {
        uint32_t m = x[i] & 0x7FFFFFFFu;
        atomicAdd(&hh[m >> FINE_BITS], 1u);
        myz += (m == 0u);
        if (m >= PIVOT_BITS) { uint32_t p = atomicAdd(&bcnt, 1u); if (p < CAP) region[p] = m; }
    }
    if (myz) atomicAdd(&zc, myz);
    __syncthreads();
    for (int i = threadIdx.x; i < (int)NCOARSE; i += 256) {
        uint32_t c = h[0][i] + h[1][i];
        if (c) atomicAdd(&ws[WS_COARSE + i], c);
    }
    if (threadIdx.x == 0) {
        if (zc) atomicAdd(&ws[WS_CTRL + 4], zc);
        ws[WS_BCNT + blockIdx.x] = bcnt;
        if (bcnt > CAP) atomicOr(&ws[WS_CTRL + 5], 1u);
    }
}

__global__ __launch_bounds__(256) void k_select_coarse(uint32_t* __restrict__ ws, int n) {
    __shared__ uint32_t sums[256];
    __shared__ uint32_t ex[256];
    __shared__ uint32_t tgt;
    const int t = threadIdx.x;
    uint32_t local[16];
    uint32_t s = 0;
    for (int i = 0; i < 16; ++i) { local[i] = ws[WS_COARSE + t * 16 + i]; s += local[i]; }
    sums[t] = s;
    __syncthreads();
    if (t == 0) {
        uint32_t zeros = ws[WS_CTRL + 4];
        uint32_t nnz = (uint32_t)n - zeros;
        // replicate reference: floor(f32(0.997) * f32(nnz)) + zeros, clamp to n-1
        long long idx = (long long)floorf(0.997f * (float)nnz) + (long long)zeros;
        if (idx > (long long)n - 1) idx = (long long)n - 1;
        tgt = (uint32_t)idx;
        uint32_t run = 0;
        for (int i = 0; i < 256; ++i) { ex[i] = run; run += sums[i]; }
    }
    __syncthreads();
    const uint32_t r = tgt;
    if (r >= ex[t] && r < ex[t] + sums[t]) {
        uint32_t run = ex[t];
        for (int i = 0; i < 16; ++i) {
            if (r < run + local[i]) {
                uint32_t b = (uint32_t)(t * 16 + i);
                ws[WS_CTRL + 0] = b;
                ws[WS_CTRL + 1] = r - run;
                // compacted regions usable iff bucket fully above pivot and no overflow
                ws[WS_CTRL + 3] = (b >= (PIVOT_BITS >> FINE_BITS) && ws[WS_CTRL + 5] == 0u) ? 1u : 0u;
                break;
            }
            run += local[i];
        }
    }
}

// fine histogram from compacted candidates (normal path, ~12 MB read)
__global__ __launch_bounds__(256) void k_fine_c(uint32_t* __restrict__ ws) {
    if (ws[WS_CTRL + 3] == 0u) return;
    const uint32_t b = ws[WS_CTRL + 0];
    uint32_t cnt = ws[WS_BCNT + blockIdx.x];
    if (cnt > CAP) cnt = CAP;
    const uint32_t* region = ws + WS_CAND + (size_t)blockIdx.x * CAP;
    for (uint32_t i = threadIdx.x; i < cnt; i += 256u) {
        uint32_t m = region[i];
        if ((m >> FINE_BITS) == b) atomicAdd(&ws[WS_FINE + (m & (NFINE - 1u))], 1u);
    }
}

// full-scan fallback (th below pivot or region overflow) — early-exits otherwise
__global__ __launch_bounds__(256) void k_fine_full(const uint32_t* __restrict__ x,
                                                   int n, uint32_t* __restrict__ ws) {
    if (ws[WS_CTRL + 3] != 0u) return;
    const uint32_t b = ws[WS_CTRL + 0];
    const int n4 = n >> 2;
    const uint4* x4 = (const uint4*)x;
    const int stride = gridDim.x * blockDim.x;
    for (int i = blockIdx.x * blockDim.x + threadIdx.x; i < n4; i += stride) {
        uint4 v = x4[i];
        uint32_t m;
        m = v.x & 0x7FFFFFFFu; if ((m >> FINE_BITS) == b) atomicAdd(&ws[WS_FINE + (m & (NFINE - 1u))], 1u);
        m = v.y & 0x7FFFFFFFu; if ((m >> FINE_BITS) == b) atomicAdd(&ws[WS_FINE + (m & (NFINE - 1u))], 1u);
        m = v.z & 0x7FFFFFFFu; if ((m >> FINE_BITS) == b) atomicAdd(&ws[WS_FINE + (m & (NFINE - 1u))], 1u);
        m = v.w & 0x7FFFFFFFu; if ((m >> FINE_BITS) == b) atomicAdd(&ws[WS_FINE + (m & (NFINE - 1u))], 1u);
    }
    for (int i = (n4 << 2) + blockIdx.x * blockDim.x + threadIdx.x; i < n; i += stride) {
        uint32_t m = x[i] & 0x7FFFFFFFu;
        if ((m >> FINE_BITS) == b) atomicAdd(&ws[WS_FINE + (m & (NFINE - 1u))], 1u);
    }
}

__global__ __launch_bounds__(256) void k_partials(uint32_t* __restrict__ ws) {
    __shared__ uint32_t red[256];
    const int t = threadIdx.x, j = blockIdx.x;
    uint32_t s = 0;
    for (int k = 0; k < CHUNK / 256; ++k) s += ws[WS_FINE + j * CHUNK + k * 256 + t];
    red[t] = s;
    __syncthreads();
    for (int o = 128; o > 0; o >>= 1) {
        if (t < o) red[t] += red[t + o];
        __syncthreads();
    }
    if (t == 0) ws[WS_PART + j] = red[0];
}

__global__ __launch_bounds__(256) void k_select_fine(uint32_t* __restrict__ ws) {
    __shared__ uint32_t sums[256];
    __shared__ uint32_t ex[256];
    __shared__ uint32_t chunk, r3;
    const int t = threadIdx.x;
    sums[t] = ws[WS_PART + t];
    __syncthreads();
    if (t == 0) {
        uint32_t r2 = ws[WS_CTRL + 1];
        uint32_t run = 0; int c = -1; uint32_t rr = 0;
        for (int i = 0; i < 256; ++i) {
            if (c < 0 && r2 < run + sums[i]) { c = i; rr = r2 - run; }
            run += sums[i];
        }
        chunk = (uint32_t)c;
        r3 = rr;
    }
    __syncthreads();
    const uint32_t c = chunk;
    uint32_t local[CHUNK / 256];
    uint32_t s = 0;
    for (int k = 0; k < CHUNK / 256; ++k) {
        local[k] = ws[WS_FINE + c * CHUNK + t * (CHUNK / 256) + k];
        s += local[k];
    }
    sums[t] = s;
    __syncthreads();
    if (t == 0) {
        uint32_t run = 0;
        for (int i = 0; i < 256; ++i) { ex[i] = run; run += sums[i]; }
    }
    __syncthreads();
    const uint32_t r = r3;
    if (r >= ex[t] && r < ex[t] + s) {
        uint32_t run = ex[t];
        for (int k = 0; k < CHUNK / 256; ++k) {
            if (r < run + local[k]) {
                uint32_t f = c * CHUNK + (uint32_t)t * (CHUNK / 256) + (uint32_t)k;
                uint32_t b = ws[WS_CTRL + 0];
                ws[WS_CTRL + 2] = (b << FINE_BITS) | f;
                break;
            }
            run += local[k];
        }
    }
}

__device__ __forceinline__ float ol_q(float v, float th, float step) {
    float q = rintf(v / step) * step;   // rintf == v_rndne == jnp.round (half-to-even)
    return (th > 0.0f && fabsf(v) <= th) ? q : v;
}

__global__ __launch_bounds__(256) void k_quant(const float* __restrict__ x,
                                               float* __restrict__ out,
                                               const uint32_t* __restrict__ ws, int n) {
    const float th = __uint_as_float(ws[WS_CTRL + 2]);
    const float step = th / 7.0f;      // n_lv_pos = 2^(4-1)-1 = 7
    const int n4 = n >> 2;
    const float4* x4 = (const float4*)x;
    float4* o4 = (float4*)out;
    const int stride = gridDim.x * blockDim.x;
    for (int i = blockIdx.x * blockDim.x + threadIdx.x; i < n4; i += stride) {
        float4 v = x4[i];
        float4 o;
        o.x = ol_q(v.x, th, step);
        o.y = ol_q(v.y, th, step);
        o.z = ol_q(v.z, th, step);
        o.w = ol_q(v.w, th, step);
        o4[i] = o;
    }
    for (int i = (n4 << 2) + blockIdx.x * blockDim.x + threadIdx.x; i < n; i += stride) {
        out[i] = ol_q(x[i], th, step);
    }
}

extern "C" void kernel_launch(void* const* d_in, const int* in_sizes, int n_in,
                              void* d_out, int out_size, void* d_ws, size_t ws_size,
                              hipStream_t stream) {
    const float* x = (const float*)d_in[0];
    const uint32_t* xb = (const uint32_t*)d_in[0];
    float* out = (float*)d_out;
    uint32_t* ws = (uint32_t*)d_ws;
    const int n = in_sizes[0];

    // zero ctrl + histograms + per-block counts (~2.1 MB; candidate regions not zeroed)
    hipMemsetAsync(d_ws, 0, (size_t)WS_ZERO_WORDS * sizeof(uint32_t), stream);

    k_histc<<<NBLOCKS, 256, 0, stream>>>(xb, n, ws);
    k_select_coarse<<<1, 256, 0, stream>>>(ws, n);
    k_fine_c<<<NBLOCKS, 256, 0, stream>>>(ws);
    k_fine_full<<<NBLOCKS, 256, 0, stream>>>(xb, n, ws);   // early-exits on normal path
    k_partials<<<NPART, 256, 0, stream>>>(ws);
    k_select_fine<<<1, 256, 0, stream>>>(ws);
    k_quant<<<NBLOCKS, 256, 0, stream>>>(x, out, ws, n);
}